// Round 1
// baseline (3649.244 us; speedup 1.0000x reference)
//
#include <hip/hip_runtime.h>
#include <math.h>

#define NEG_BIG -3.402823466e38f
#define SCALE_ATTN 0.07216878364870323f   /* 192^-0.5 */
#define IW_SCALE   0.011048543456039806f  /* (64*128)^-0.5 */

// ---------------------------------------------------------------------------
// Generic f32 tiled GEMM: C = alpha * A(MxK) * B
//   BT=true : B is (N x K) row-major  -> C[m,n] = sum_k A[m,k]*B[n,k]
//   BT=false: B is (K x N) row-major  -> C[m,n] = sum_k A[m,k]*B[k,n]
// Requires: M%64==0, N%64==0, K%16==0, all lds multiples of 4.
// ---------------------------------------------------------------------------
template<bool BT>
__global__ __launch_bounds__(256) void gemm_f32(
    const float* __restrict__ A, const float* __restrict__ B, float* __restrict__ C,
    int M, int N, int K, int lda, int ldb, int ldc,
    long long sA, long long sB, long long sC, float alpha)
{
  __shared__ float As[16][68];
  __shared__ float Bs[16][68];
  A += (long long)blockIdx.z * sA;
  B += (long long)blockIdx.z * sB;
  C += (long long)blockIdx.z * sC;
  const int m0 = blockIdx.y * 64;
  const int n0 = blockIdx.x * 64;
  const int t  = threadIdx.x;
  const int tx = t & 15, ty = t >> 4;
  float acc[4][4] = {};
  for (int k0 = 0; k0 < K; k0 += 16) {
    {
      const int m  = t >> 2;
      const int k4 = (t & 3) << 2;
      float4 v = *reinterpret_cast<const float4*>(&A[(long long)(m0 + m) * lda + k0 + k4]);
      As[k4 + 0][m] = v.x; As[k4 + 1][m] = v.y; As[k4 + 2][m] = v.z; As[k4 + 3][m] = v.w;
    }
    if (BT) {
      const int n  = t >> 2;
      const int k4 = (t & 3) << 2;
      float4 v = *reinterpret_cast<const float4*>(&B[(long long)(n0 + n) * ldb + k0 + k4]);
      Bs[k4 + 0][n] = v.x; Bs[k4 + 1][n] = v.y; Bs[k4 + 2][n] = v.z; Bs[k4 + 3][n] = v.w;
    } else {
      const int k  = t >> 4;
      const int n4 = (t & 15) << 2;
      float4 v = *reinterpret_cast<const float4*>(&B[(long long)(k0 + k) * ldb + n0 + n4]);
      *reinterpret_cast<float4*>(&Bs[k][n4]) = v;
    }
    __syncthreads();
    #pragma unroll
    for (int kk = 0; kk < 16; ++kk) {
      float4 a = *reinterpret_cast<const float4*>(&As[kk][ty << 2]);
      float4 b = *reinterpret_cast<const float4*>(&Bs[kk][tx << 2]);
      float av[4] = {a.x, a.y, a.z, a.w};
      float bv[4] = {b.x, b.y, b.z, b.w};
      #pragma unroll
      for (int i = 0; i < 4; ++i)
        #pragma unroll
        for (int j = 0; j < 4; ++j)
          acc[i][j] = fmaf(av[i], bv[j], acc[i][j]);
    }
    __syncthreads();
  }
  #pragma unroll
  for (int i = 0; i < 4; ++i) {
    float4 v = make_float4(acc[i][0] * alpha, acc[i][1] * alpha,
                           acc[i][2] * alpha, acc[i][3] * alpha);
    *reinterpret_cast<float4*>(&C[(long long)(m0 + (ty << 2) + i) * ldc + n0 + (tx << 2)]) = v;
  }
}

// ---------------------------------------------------------------------------
// Row-wise RMSNorm in place over first N columns of rows with stride ld.
// ---------------------------------------------------------------------------
__global__ __launch_bounds__(256) void rmsnorm_rows(
    float* __restrict__ y, const float* __restrict__ w, int N, int ld, float eps)
{
  const int row = blockIdx.x;
  float* p = y + (long long)row * ld;
  float ss = 0.f;
  for (int i = threadIdx.x; i < N; i += 256) { float v = p[i]; ss += v * v; }
  __shared__ float red[4];
  #pragma unroll
  for (int o = 32; o; o >>= 1) ss += __shfl_down(ss, o);
  if ((threadIdx.x & 63) == 0) red[threadIdx.x >> 6] = ss;
  __syncthreads();
  if (threadIdx.x == 0) {
    float s = red[0] + red[1] + red[2] + red[3];
    red[0] = rsqrtf(s / (float)N + eps);
  }
  __syncthreads();
  const float sc = red[0];
  for (int i = threadIdx.x; i < N; i += 256) p[i] = p[i] * sc * w[i];
}

// ---------------------------------------------------------------------------
// Row-wise LayerNorm in place, N == 128, 128 threads/block.
// ---------------------------------------------------------------------------
__global__ __launch_bounds__(128) void layernorm_rows(
    float* __restrict__ y, const float* __restrict__ w, const float* __restrict__ b,
    float eps)
{
  const int row = blockIdx.x;
  float* p = y + (long long)row * 128;
  float v = p[threadIdx.x];
  __shared__ float red[2];
  float s = v;
  #pragma unroll
  for (int o = 32; o; o >>= 1) s += __shfl_down(s, o);
  if ((threadIdx.x & 63) == 0) red[threadIdx.x >> 6] = s;
  __syncthreads();
  const float mu = (red[0] + red[1]) * (1.f / 128.f);
  const float d = v - mu;
  float s2 = d * d;
  #pragma unroll
  for (int o = 32; o; o >>= 1) s2 += __shfl_down(s2, o);
  __syncthreads();
  if ((threadIdx.x & 63) == 0) red[threadIdx.x >> 6] = s2;
  __syncthreads();
  const float var = (red[0] + red[1]) * (1.f / 128.f);
  p[threadIdx.x] = d * rsqrtf(var + eps) * w[threadIdx.x] + b[threadIdx.x];
}

// ---------------------------------------------------------------------------
// Traditional (interleaved-pair) RoPE in place, 64-dim slice, pos = blockIdx.x.
// grid (L, nHeads), 32 threads (one pair each).
// ---------------------------------------------------------------------------
__global__ void rope_apply(float* __restrict__ buf, int rowStride, int headStride, int dOff)
{
  const int l = blockIdx.x, h = blockIdx.y, i = threadIdx.x;
  const float inv = powf(10000.f, -(float)(2 * i) / 64.f);
  const float ang = (float)l * inv;
  const float c = cosf(ang), s = sinf(ang);
  float* pp = buf + (long long)l * rowStride + (long long)h * headStride + dOff + 2 * i;
  const float x1 = pp[0], x2 = pp[1];
  pp[0] = x1 * c - x2 * s;
  pp[1] = x1 * s + x2 * c;
}

// ---------------------------------------------------------------------------
// Indexer scores: S[l][s] = sum_h iw[l][h] * relu( iq[l][h][:] . ik[s][:] )
// 64x64 output tiles, lower-triangular only. K=128 split in two 64 chunks.
// ---------------------------------------------------------------------------
__global__ __launch_bounds__(256) void indexer_scores(
    const float* __restrict__ iq,   // [1024][64*128]
    const float* __restrict__ ik,   // [1024][128]
    const float* __restrict__ iw,   // [1024][64]
    float* __restrict__ S)          // [1024][1024]
{
  const int lb = blockIdx.y, sb = blockIdx.x;
  if (sb > lb) return;
  __shared__ float iks[2][64][68];
  __shared__ float iqs[64][68];
  const int t = threadIdx.x;
  const int tx = t & 15, ty = t >> 4;
  const int l0 = lb * 64, s0 = sb * 64;
  // stage ik tile (both K-chunks) once: 64 rows x 128
  #pragma unroll
  for (int r = 0; r < 8; ++r) {
    int flat = (r * 256 + t) * 4;
    int s  = flat >> 7;
    int kk = flat & 127;
    float4 v = *reinterpret_cast<const float4*>(&ik[(long long)(s0 + s) * 128 + kk]);
    int kc = kk >> 6, kr = kk & 63;
    iks[kc][kr + 0][s] = v.x; iks[kc][kr + 1][s] = v.y;
    iks[kc][kr + 2][s] = v.z; iks[kc][kr + 3][s] = v.w;
  }
  float acc[4][4] = {};
  for (int h = 0; h < 64; ++h) {
    float tmp[4][4] = {};
    for (int kc = 0; kc < 2; ++kc) {
      __syncthreads();
      #pragma unroll
      for (int r = 0; r < 4; ++r) {
        int flat = (r * 256 + t) * 4;
        int li = flat >> 6;
        int kk = flat & 63;
        float4 v = *reinterpret_cast<const float4*>(
            &iq[(long long)(l0 + li) * 8192 + h * 128 + kc * 64 + kk]);
        iqs[kk + 0][li] = v.x; iqs[kk + 1][li] = v.y;
        iqs[kk + 2][li] = v.z; iqs[kk + 3][li] = v.w;
      }
      __syncthreads();
      #pragma unroll
      for (int kk = 0; kk < 64; ++kk) {
        float4 a = *reinterpret_cast<const float4*>(&iqs[kk][ty << 2]);
        float4 b = *reinterpret_cast<const float4*>(&iks[kc][kk][tx << 2]);
        float av[4] = {a.x, a.y, a.z, a.w};
        float bv[4] = {b.x, b.y, b.z, b.w};
        #pragma unroll
        for (int i = 0; i < 4; ++i)
          #pragma unroll
          for (int j = 0; j < 4; ++j)
            tmp[i][j] = fmaf(av[i], bv[j], tmp[i][j]);
      }
    }
    #pragma unroll
    for (int i = 0; i < 4; ++i) {
      float wv = iw[(long long)(l0 + (ty << 2) + i) * 64 + h];
      #pragma unroll
      for (int j = 0; j < 4; ++j)
        acc[i][j] += wv * fmaxf(tmp[i][j], 0.f);
    }
  }
  #pragma unroll
  for (int i = 0; i < 4; ++i) {
    int l = l0 + (ty << 2) + i;
    #pragma unroll
    for (int j = 0; j < 4; ++j) {
      int s = s0 + (tx << 2) + j;
      S[(long long)l * 1024 + s] = (s <= l) ? acc[i][j] : NEG_BIG;
    }
  }
}

// ---------------------------------------------------------------------------
// Per-row top-k (k = min(256, l+1)) via 4-pass radix select on monotonic keys.
// One 256-thread block per row.
// ---------------------------------------------------------------------------
__global__ __launch_bounds__(256) void topk_rows(
    const float* __restrict__ S, int* __restrict__ idx_out, int* __restrict__ cnt_out)
{
  const int l = blockIdx.x;
  const int n = l + 1;
  const int k = n < 256 ? n : 256;
  if (threadIdx.x == 0) cnt_out[l] = k;
  if (k == n) {  // all causal positions selected
    for (int s = threadIdx.x; s < n; s += 256) idx_out[l * 256 + s] = s;
    return;
  }
  __shared__ unsigned u[1024];
  __shared__ int hist[256];
  __shared__ unsigned sh_pref;
  __shared__ int sh_rem, cG, cE;
  const float* row = S + (long long)l * 1024;
  for (int s = threadIdx.x; s < n; s += 256) {
    unsigned b = __float_as_uint(row[s]);
    u[s] = (b & 0x80000000u) ? ~b : (b | 0x80000000u);
  }
  __syncthreads();
  unsigned prefix = 0;
  int rem = k;
  for (int pass = 0; pass < 4; ++pass) {
    const int shift = 24 - 8 * pass;
    hist[threadIdx.x] = 0;
    __syncthreads();
    const unsigned hiMask = (pass == 0) ? 0u : (0xFFFFFFFFu << (shift + 8));
    for (int s = threadIdx.x; s < n; s += 256) {
      unsigned uv = u[s];
      if ((uv & hiMask) == (prefix & hiMask))
        atomicAdd(&hist[(uv >> shift) & 255], 1);
    }
    __syncthreads();
    if (threadIdx.x == 0) {
      int cum = 0, b = 255;
      for (; b > 0; --b) { cum += hist[b]; if (cum >= rem) break; }
      if (cum < rem) cum += hist[0];  // b==0 fallthrough
      sh_rem  = rem - (cum - hist[b]);
      sh_pref = prefix | ((unsigned)b << shift);
    }
    __syncthreads();
    prefix = sh_pref;
    rem = sh_rem;
    __syncthreads();
  }
  if (threadIdx.x == 0) { cG = 0; cE = 0; }
  __syncthreads();
  for (int s = threadIdx.x; s < n; s += 256) {
    if (u[s] > prefix) { int p = atomicAdd(&cG, 1); idx_out[l * 256 + p] = s; }
  }
  __syncthreads();
  const int base = cG;
  for (int s = threadIdx.x; s < n; s += 256) {
    if (u[s] == prefix) {
      int p = atomicAdd(&cE, 1);
      if (p < rem) idx_out[l * 256 + base + p] = s;
    }
  }
}

// ---------------------------------------------------------------------------
// Sparse attention: grid (L, H), 256 threads.
// score_i = SCALE * ( q_nope . k[h][j] + q_pe . k_pe[j] ); softmax; out = P.V
// ---------------------------------------------------------------------------
__global__ __launch_bounds__(256) void sparse_attn(
    const float* __restrict__ qbuf,   // [1024][32*192] (pe part already roped)
    const float* __restrict__ ckv,    // [1024][576] (cols 512..575 = roped k_pe)
    const float* __restrict__ kbuf,   // [32][1024][128]
    const float* __restrict__ vbuf,   // [32][1024][128]
    const int* __restrict__ topk_idx, const int* __restrict__ topk_cnt,
    float* __restrict__ attn_out)     // [1024][32*128]
{
  const int l = blockIdx.x, h = blockIdx.y, t = threadIdx.x;
  const int cnt = topk_cnt[l];
  __shared__ float qs[192];
  __shared__ float p[256];
  __shared__ int   jl[256];
  __shared__ float red[8];
  if (t < 192) qs[t] = qbuf[(long long)l * 6144 + h * 192 + t];
  if (t < cnt) jl[t] = topk_idx[l * 256 + t];
  __syncthreads();
  float sc = NEG_BIG;
  if (t < cnt) {
    const int j = jl[t];
    const float* kr = kbuf + ((long long)h * 1024 + j) * 128;
    const float* pe = ckv + (long long)j * 576 + 512;
    float acc = 0.f;
    #pragma unroll 8
    for (int d = 0; d < 128; ++d) acc += qs[d] * kr[d];
    #pragma unroll 8
    for (int d = 0; d < 64; ++d) acc += qs[128 + d] * pe[d];
    sc = acc * SCALE_ATTN;
  }
  float mx = sc;
  #pragma unroll
  for (int o = 32; o; o >>= 1) mx = fmaxf(mx, __shfl_down(mx, o));
  if ((t & 63) == 0) red[t >> 6] = mx;
  __syncthreads();
  if (t == 0) {
    float m = fmaxf(fmaxf(red[0], red[1]), fmaxf(red[2], red[3]));
    red[0] = m;
  }
  __syncthreads();
  mx = red[0];
  float e = (t < cnt) ? expf(sc - mx) : 0.f;
  float sm = e;
  #pragma unroll
  for (int o = 32; o; o >>= 1) sm += __shfl_down(sm, o);
  if ((t & 63) == 0) red[4 + (t >> 6)] = sm;
  __syncthreads();
  if (t == 0) red[4] = red[4] + red[5] + red[6] + red[7];
  __syncthreads();
  p[t] = e / red[4];
  __syncthreads();
  if (t < 128) {
    float acc = 0.f;
    for (int i = 0; i < cnt; ++i)
      acc += p[i] * vbuf[((long long)h * 1024 + jl[i]) * 128 + t];
    attn_out[(long long)l * 4096 + h * 128 + t] = acc;
  }
}

// ---------------------------------------------------------------------------
extern "C" void kernel_launch(void* const* d_in, const int* in_sizes, int n_in,
                              void* d_out, int out_size, void* d_ws, size_t ws_size,
                              hipStream_t stream)
{
  const float* x        = (const float*)d_in[0];
  // d_in[1] = mask (causal tril) — implicit in kernels
  const float* W_qa     = (const float*)d_in[2];
  const float* qa_ln_w  = (const float*)d_in[3];
  const float* W_qb     = (const float*)d_in[4];
  const float* W_kva    = (const float*)d_in[5];
  const float* kva_ln_w = (const float*)d_in[6];
  const float* W_eq     = (const float*)d_in[7];   // [32][512][128]
  const float* W_uo     = (const float*)d_in[8];   // [32][128][512]
  const float* W_o      = (const float*)d_in[9];   // [4096][4096]
  const float* idx_wqb  = (const float*)d_in[10];  // [8192][1536]
  const float* idx_wk   = (const float*)d_in[11];  // [128][4096]
  const float* idx_klnw = (const float*)d_in[12];
  const float* idx_klnb = (const float*)d_in[13];
  const float* idx_wprj = (const float*)d_in[14];  // [64][4096]
  float* out = (float*)d_out;

  float* ws = (float*)d_ws;
  float* qr       = ws; ws += 1024 * 1536;
  float* qbuf     = ws; ws += 1024 * 6144;
  float* ckv      = ws; ws += 1024 * 576;
  float* iqbuf    = ws; ws += 1024 * 8192;
  float* ikbuf    = ws; ws += 1024 * 128;
  float* iwbuf    = ws; ws += 1024 * 64;
  float* iscores  = ws; ws += 1024 * 1024;
  float* kbuf     = ws; ws += 32 * 1024 * 128;
  float* vbuf     = ws; ws += 32 * 1024 * 128;
  float* attn_out = ws; ws += 1024 * 4096;
  int* tk_idx = (int*)ws; ws += 1024 * 256;
  int* tk_cnt = (int*)ws;

  // 1) qr = rmsnorm(x @ W_qa.T)
  gemm_f32<true><<<dim3(1536 / 64, 1024 / 64, 1), 256, 0, stream>>>(
      x, W_qa, qr, 1024, 1536, 4096, 4096, 4096, 1536, 0, 0, 0, 1.f);
  rmsnorm_rows<<<1024, 256, 0, stream>>>(qr, qa_ln_w, 1536, 1536, 1e-6f);

  // 2) ckv = x @ W_kva.T ; rmsnorm first 512 ; rope k_pe (cols 512..575)
  gemm_f32<true><<<dim3(576 / 64, 1024 / 64, 1), 256, 0, stream>>>(
      x, W_kva, ckv, 1024, 576, 4096, 4096, 4096, 576, 0, 0, 0, 1.f);
  rmsnorm_rows<<<1024, 256, 0, stream>>>(ckv, kva_ln_w, 512, 576, 1e-6f);
  rope_apply<<<dim3(1024, 1), 32, 0, stream>>>(ckv, 576, 0, 512);

  // 3) q = qr @ W_qb.T ; rope q_pe (dims 128..191 per 192-head)
  gemm_f32<true><<<dim3(6144 / 64, 1024 / 64, 1), 256, 0, stream>>>(
      qr, W_qb, qbuf, 1024, 6144, 1536, 1536, 1536, 6144, 0, 0, 0, 1.f);
  rope_apply<<<dim3(1024, 32), 32, 0, stream>>>(qbuf, 6144, 192, 128);

  // 4) iq = qr @ idx_wqb.T ; rope first 64 of each 128-head
  gemm_f32<true><<<dim3(8192 / 64, 1024 / 64, 1), 256, 0, stream>>>(
      qr, idx_wqb, iqbuf, 1024, 8192, 1536, 1536, 1536, 8192, 0, 0, 0, 1.f);
  rope_apply<<<dim3(1024, 64), 32, 0, stream>>>(iqbuf, 8192, 128, 0);

  // 5) ik = rope(layernorm(x @ idx_wk.T))
  gemm_f32<true><<<dim3(128 / 64, 1024 / 64, 1), 256, 0, stream>>>(
      x, idx_wk, ikbuf, 1024, 128, 4096, 4096, 4096, 128, 0, 0, 0, 1.f);
  layernorm_rows<<<1024, 128, 0, stream>>>(ikbuf, idx_klnw, idx_klnb, 1e-5f);
  rope_apply<<<dim3(1024, 1), 32, 0, stream>>>(ikbuf, 128, 0, 0);

  // 6) iw = x @ idx_wproj.T * (64*128)^-0.5
  gemm_f32<true><<<dim3(64 / 64, 1024 / 64, 1), 256, 0, stream>>>(
      x, idx_wprj, iwbuf, 1024, 64, 4096, 4096, 4096, 64, 0, 0, 0, IW_SCALE);

  // 7) indexer scores (head-summed, relu-weighted) ; 8) top-k per row
  indexer_scores<<<dim3(16, 16), 256, 0, stream>>>(iqbuf, ikbuf, iwbuf, iscores);
  topk_rows<<<1024, 256, 0, stream>>>(iscores, tk_idx, tk_cnt);

  // 9) k[h] = kv_lat @ W_eq[h] (NN) ; v[h] = kv_lat @ W_uo[h].T (NT), batched over h
  gemm_f32<false><<<dim3(2, 16, 32), 256, 0, stream>>>(
      ckv, W_eq, kbuf, 1024, 128, 512, 576, 128, 128,
      0LL, 512LL * 128, 1024LL * 128, 1.f);
  gemm_f32<true><<<dim3(2, 16, 32), 256, 0, stream>>>(
      ckv, W_uo, vbuf, 1024, 128, 512, 576, 512, 128,
      0LL, 128LL * 512, 1024LL * 128, 1.f);

  // 10) sparse attention
  sparse_attn<<<dim3(1024, 32), 256, 0, stream>>>(
      qbuf, ckv, kbuf, vbuf, tk_idx, tk_cnt, attn_out);

  // 11) out = attn_out @ W_o.T
  gemm_f32<true><<<dim3(4096 / 64, 1024 / 64, 1), 256, 0, stream>>>(
      attn_out, W_o, out, 1024, 4096, 4096, 4096, 4096, 4096, 0, 0, 0, 1.f);
}

// Round 3
// 1872.077 us; speedup vs baseline: 1.9493x; 1.9493x over previous
//
#include <hip/hip_runtime.h>
#include <math.h>

#define NEG_BIG -3.402823466e38f
#define SCALE_ATTN 0.07216878364870323f   /* 192^-0.5 */
#define IW_SCALE   0.011048543456039806f  /* (64*128)^-0.5 */

typedef __attribute__((ext_vector_type(8))) short  bf16x8;
typedef __attribute__((ext_vector_type(4))) float  f32x4;

__device__ __forceinline__ unsigned short f2bf(float f) {
  unsigned u = __float_as_uint(f);
  unsigned r = (u + 0x7FFFu + ((u >> 16) & 1u)) >> 16;
  return (unsigned short)r;
}

// ---------------------------------------------------------------------------
// f32 tiled GEMM 64x64x16 (NT / NN), batched/split-K via sA/sB/sC.
// ---------------------------------------------------------------------------
template<bool BT>
__global__ __launch_bounds__(256) void gemm_f32(
    const float* __restrict__ A, const float* __restrict__ B, float* __restrict__ C,
    int M, int N, int K, int lda, int ldb, int ldc,
    long long sA, long long sB, long long sC, float alpha)
{
  __shared__ float As[16][68];
  __shared__ float Bs[16][68];
  A += (long long)blockIdx.z * sA;
  B += (long long)blockIdx.z * sB;
  C += (long long)blockIdx.z * sC;
  const int m0 = blockIdx.y * 64;
  const int n0 = blockIdx.x * 64;
  const int t  = threadIdx.x;
  const int tx = t & 15, ty = t >> 4;
  float acc[4][4] = {};
  for (int k0 = 0; k0 < K; k0 += 16) {
    {
      const int m  = t >> 2;
      const int k4 = (t & 3) << 2;
      float4 v = *reinterpret_cast<const float4*>(&A[(long long)(m0 + m) * lda + k0 + k4]);
      As[k4 + 0][m] = v.x; As[k4 + 1][m] = v.y; As[k4 + 2][m] = v.z; As[k4 + 3][m] = v.w;
    }
    if (BT) {
      const int n  = t >> 2;
      const int k4 = (t & 3) << 2;
      float4 v = *reinterpret_cast<const float4*>(&B[(long long)(n0 + n) * ldb + k0 + k4]);
      Bs[k4 + 0][n] = v.x; Bs[k4 + 1][n] = v.y; Bs[k4 + 2][n] = v.z; Bs[k4 + 3][n] = v.w;
    } else {
      const int k  = t >> 4;
      const int n4 = (t & 15) << 2;
      float4 v = *reinterpret_cast<const float4*>(&B[(long long)(k0 + k) * ldb + n0 + n4]);
      *reinterpret_cast<float4*>(&Bs[k][n4]) = v;
    }
    __syncthreads();
    #pragma unroll
    for (int kk = 0; kk < 16; ++kk) {
      float4 a = *reinterpret_cast<const float4*>(&As[kk][ty << 2]);
      float4 b = *reinterpret_cast<const float4*>(&Bs[kk][tx << 2]);
      float av[4] = {a.x, a.y, a.z, a.w};
      float bv[4] = {b.x, b.y, b.z, b.w};
      #pragma unroll
      for (int i = 0; i < 4; ++i)
        #pragma unroll
        for (int j = 0; j < 4; ++j)
          acc[i][j] = fmaf(av[i], bv[j], acc[i][j]);
    }
    __syncthreads();
  }
  #pragma unroll
  for (int i = 0; i < 4; ++i) {
    float4 v = make_float4(acc[i][0] * alpha, acc[i][1] * alpha,
                           acc[i][2] * alpha, acc[i][3] * alpha);
    *reinterpret_cast<float4*>(&C[(long long)(m0 + (ty << 2) + i) * ldc + n0 + (tx << 2)]) = v;
  }
}

// ---------------------------------------------------------------------------
// f32 tiled GEMM 128x128x16 NT, 8x8 acc per thread. batched/splitK via strides.
// ---------------------------------------------------------------------------
__global__ __launch_bounds__(256) void gemm_f32_128(
    const float* __restrict__ A, const float* __restrict__ B, float* __restrict__ C,
    int K, int lda, int ldb, int ldc,
    long long sA, long long sB, long long sC, float alpha)
{
  __shared__ float As[16][132];
  __shared__ float Bs[16][132];
  A += (long long)blockIdx.z * sA;
  B += (long long)blockIdx.z * sB;
  C += (long long)blockIdx.z * sC;
  const int m0 = blockIdx.y * 128, n0 = blockIdx.x * 128;
  const int t = threadIdx.x;
  const int tx = t & 15, ty = t >> 4;
  float acc[8][8] = {};
  for (int k0 = 0; k0 < K; k0 += 16) {
    #pragma unroll
    for (int c = 0; c < 2; ++c) {
      const int idx = c * 256 + t;
      const int row = idx >> 2;
      const int k4 = (idx & 3) << 2;
      float4 va = *reinterpret_cast<const float4*>(&A[(long long)(m0 + row) * lda + k0 + k4]);
      As[k4+0][row]=va.x; As[k4+1][row]=va.y; As[k4+2][row]=va.z; As[k4+3][row]=va.w;
      float4 vb = *reinterpret_cast<const float4*>(&B[(long long)(n0 + row) * ldb + k0 + k4]);
      Bs[k4+0][row]=vb.x; Bs[k4+1][row]=vb.y; Bs[k4+2][row]=vb.z; Bs[k4+3][row]=vb.w;
    }
    __syncthreads();
    #pragma unroll
    for (int kk = 0; kk < 16; ++kk) {
      float a[8], b[8];
      *(float4*)&a[0] = *(const float4*)&As[kk][ty * 8];
      *(float4*)&a[4] = *(const float4*)&As[kk][ty * 8 + 4];
      *(float4*)&b[0] = *(const float4*)&Bs[kk][tx * 8];
      *(float4*)&b[4] = *(const float4*)&Bs[kk][tx * 8 + 4];
      #pragma unroll
      for (int i = 0; i < 8; ++i)
        #pragma unroll
        for (int j = 0; j < 8; ++j)
          acc[i][j] = fmaf(a[i], b[j], acc[i][j]);
    }
    __syncthreads();
  }
  #pragma unroll
  for (int i = 0; i < 8; ++i) {
    const long long row = (long long)(m0 + ty * 8 + i) * ldc + n0 + tx * 8;
    float4 v0 = make_float4(acc[i][0]*alpha, acc[i][1]*alpha, acc[i][2]*alpha, acc[i][3]*alpha);
    float4 v1 = make_float4(acc[i][4]*alpha, acc[i][5]*alpha, acc[i][6]*alpha, acc[i][7]*alpha);
    *reinterpret_cast<float4*>(&C[row])     = v0;
    *reinterpret_cast<float4*>(&C[row + 4]) = v1;
  }
}

// ---------------------------------------------------------------------------
// split-K reduce: out[i] = sum_z part[z][i]  (float4 granularity)
// ---------------------------------------------------------------------------
__global__ void reduce_sk(const float* __restrict__ part, float* __restrict__ out,
                          int n4, int S)
{
  int i = blockIdx.x * 256 + threadIdx.x;
  if (i >= n4) return;
  const float4* p = (const float4*)part;
  float4 s = p[i];
  for (int z = 1; z < S; ++z) {
    float4 v = p[(long long)z * n4 + i];
    s.x += v.x; s.y += v.y; s.z += v.z; s.w += v.w;
  }
  ((float4*)out)[i] = s;
}

// ---------------------------------------------------------------------------
// f32 -> bf16 convert (float4 granularity)
// ---------------------------------------------------------------------------
__global__ void f2bf_k(const float* __restrict__ in, unsigned short* __restrict__ out, int n4)
{
  int i = blockIdx.x * 256 + threadIdx.x;
  if (i >= n4) return;
  float4 v = ((const float4*)in)[i];
  ushort4 o;
  o.x = f2bf(v.x); o.y = f2bf(v.y); o.z = f2bf(v.z); o.w = f2bf(v.w);
  ((ushort4*)out)[i] = o;
}

// ---------------------------------------------------------------------------
// bf16 NT GEMM: C = A(MxK) * B(NxK)^T, 128x128 tile, BK=64, dbuf global_load_lds,
// mfma_f32_16x16x32_bf16. M,N multiples of 128, K multiple of 64.
// ---------------------------------------------------------------------------
template<bool STORE_BF16>
__global__ __launch_bounds__(256) void gemm_bf16nt(
    const unsigned short* __restrict__ Ag, const unsigned short* __restrict__ Bg,
    void* __restrict__ Cout,
    int K, int lda, int ldb, int ldc,
    long long sA, long long sB, long long sC)
{
  __shared__ unsigned short As[2][128 * 64];
  __shared__ unsigned short Bs[2][128 * 64];
  Ag += (long long)blockIdx.z * sA;
  Bg += (long long)blockIdx.z * sB;
  const long long cz = (long long)blockIdx.z * sC;
  const int m0 = blockIdx.y * 128, n0 = blockIdx.x * 128;
  const int t = threadIdx.x;
  const int wr = (t >> 7) & 1;        // wave row (w>>1)
  const int wc = (t >> 6) & 1;        // wave col (w&1)
  f32x4 acc[4][4] = {};

#define STAGE_TILE(buf, kt) do {                                              \
    const int k0s = (kt) * 64;                                                \
    _Pragma("unroll")                                                         \
    for (int c = 0; c < 4; ++c) {                                             \
      const int idx = c * 256 + t;                                            \
      const int row = idx >> 3;                                               \
      const int col = (idx & 7) << 3;                                         \
      const unsigned short* gA = Ag + (long long)(m0 + row) * lda + k0s + col;\
      const unsigned short* gB = Bg + (long long)(n0 + row) * ldb + k0s + col;\
      __builtin_amdgcn_global_load_lds(                                       \
          (const __attribute__((address_space(1))) void*)gA,                  \
          (__attribute__((address_space(3))) void*)(&As[buf][(c * 256 + (t & 192)) << 3]), \
          16, 0, 0);                                                          \
      __builtin_amdgcn_global_load_lds(                                       \
          (const __attribute__((address_space(1))) void*)gB,                  \
          (__attribute__((address_space(3))) void*)(&Bs[buf][(c * 256 + (t & 192)) << 3]), \
          16, 0, 0);                                                          \
    }                                                                         \
  } while (0)

  const int nt = K >> 6;
  STAGE_TILE(0, 0);
  __syncthreads();
  int cur = 0;
  for (int kt = 0; kt < nt; ++kt) {
    if (kt + 1 < nt) STAGE_TILE(cur ^ 1, kt + 1);
    #pragma unroll
    for (int kk = 0; kk < 2; ++kk) {
      const int ko = kk * 32 + ((t >> 4) & 3) * 8;
      bf16x8 af[4], bfr[4];
      #pragma unroll
      for (int mi = 0; mi < 4; ++mi)
        af[mi] = *reinterpret_cast<const bf16x8*>(&As[cur][(wr*64 + mi*16 + (t & 15)) * 64 + ko]);
      #pragma unroll
      for (int nj = 0; nj < 4; ++nj)
        bfr[nj] = *reinterpret_cast<const bf16x8*>(&Bs[cur][(wc*64 + nj*16 + (t & 15)) * 64 + ko]);
      #pragma unroll
      for (int mi = 0; mi < 4; ++mi)
        #pragma unroll
        for (int nj = 0; nj < 4; ++nj)
          acc[mi][nj] = __builtin_amdgcn_mfma_f32_16x16x32_bf16(af[mi], bfr[nj], acc[mi][nj], 0, 0, 0);
    }
    __syncthreads();
    cur ^= 1;
  }
#undef STAGE_TILE

  const int r0 = ((t >> 4) & 3) << 2;
  #pragma unroll
  for (int mi = 0; mi < 4; ++mi)
    #pragma unroll
    for (int nj = 0; nj < 4; ++nj) {
      const int col = n0 + wc * 64 + nj * 16 + (t & 15);
      #pragma unroll
      for (int r = 0; r < 4; ++r) {
        const long long off = cz + (long long)(m0 + wr * 64 + mi * 16 + r0 + r) * ldc + col;
        if constexpr (STORE_BF16)
          ((unsigned short*)Cout)[off] = f2bf(acc[mi][nj][r]);
        else
          ((float*)Cout)[off] = acc[mi][nj][r];
      }
    }
}

// ---------------------------------------------------------------------------
__global__ __launch_bounds__(256) void rmsnorm_rows(
    float* __restrict__ y, const float* __restrict__ w, int N, int ld, float eps)
{
  const int row = blockIdx.x;
  float* p = y + (long long)row * ld;
  float ss = 0.f;
  for (int i = threadIdx.x; i < N; i += 256) { float v = p[i]; ss += v * v; }
  __shared__ float red[4];
  #pragma unroll
  for (int o = 32; o; o >>= 1) ss += __shfl_down(ss, o);
  if ((threadIdx.x & 63) == 0) red[threadIdx.x >> 6] = ss;
  __syncthreads();
  if (threadIdx.x == 0) {
    float s = red[0] + red[1] + red[2] + red[3];
    red[0] = rsqrtf(s / (float)N + eps);
  }
  __syncthreads();
  const float sc = red[0];
  for (int i = threadIdx.x; i < N; i += 256) p[i] = p[i] * sc * w[i];
}

__global__ __launch_bounds__(128) void layernorm_rows(
    float* __restrict__ y, const float* __restrict__ w, const float* __restrict__ b,
    float eps)
{
  const int row = blockIdx.x;
  float* p = y + (long long)row * 128;
  float v = p[threadIdx.x];
  __shared__ float red[2];
  float s = v;
  #pragma unroll
  for (int o = 32; o; o >>= 1) s += __shfl_down(s, o);
  if ((threadIdx.x & 63) == 0) red[threadIdx.x >> 6] = s;
  __syncthreads();
  const float mu = (red[0] + red[1]) * (1.f / 128.f);
  const float d = v - mu;
  float s2 = d * d;
  #pragma unroll
  for (int o = 32; o; o >>= 1) s2 += __shfl_down(s2, o);
  __syncthreads();
  if ((threadIdx.x & 63) == 0) red[threadIdx.x >> 6] = s2;
  __syncthreads();
  const float var = (red[0] + red[1]) * (1.f / 128.f);
  p[threadIdx.x] = d * rsqrtf(var + eps) * w[threadIdx.x] + b[threadIdx.x];
}

__global__ void rope_apply(float* __restrict__ buf, int rowStride, int headStride, int dOff)
{
  const int l = blockIdx.x, h = blockIdx.y, i = threadIdx.x;
  const float inv = powf(10000.f, -(float)(2 * i) / 64.f);
  const float ang = (float)l * inv;
  const float c = cosf(ang), s = sinf(ang);
  float* pp = buf + (long long)l * rowStride + (long long)h * headStride + dOff + 2 * i;
  const float x1 = pp[0], x2 = pp[1];
  pp[0] = x1 * c - x2 * s;
  pp[1] = x1 * s + x2 * c;
}

// ---------------------------------------------------------------------------
// Indexer scores (f32, exact ranking path)
// ---------------------------------------------------------------------------
__global__ __launch_bounds__(256) void indexer_scores(
    const float* __restrict__ iq, const float* __restrict__ ik,
    const float* __restrict__ iw, float* __restrict__ S)
{
  const int lb = blockIdx.y, sb = blockIdx.x;
  if (sb > lb) return;
  __shared__ float iks[2][64][68];
  __shared__ float iqs[64][68];
  const int t = threadIdx.x;
  const int tx = t & 15, ty = t >> 4;
  const int l0 = lb * 64, s0 = sb * 64;
  #pragma unroll
  for (int r = 0; r < 8; ++r) {
    int flat = (r * 256 + t) * 4;
    int s  = flat >> 7;
    int kk = flat & 127;
    float4 v = *reinterpret_cast<const float4*>(&ik[(long long)(s0 + s) * 128 + kk]);
    int kc = kk >> 6, kr = kk & 63;
    iks[kc][kr + 0][s] = v.x; iks[kc][kr + 1][s] = v.y;
    iks[kc][kr + 2][s] = v.z; iks[kc][kr + 3][s] = v.w;
  }
  float acc[4][4] = {};
  for (int h = 0; h < 64; ++h) {
    float tmp[4][4] = {};
    for (int kc = 0; kc < 2; ++kc) {
      __syncthreads();
      #pragma unroll
      for (int r = 0; r < 4; ++r) {
        int flat = (r * 256 + t) * 4;
        int li = flat >> 6;
        int kk = flat & 63;
        float4 v = *reinterpret_cast<const float4*>(
            &iq[(long long)(l0 + li) * 8192 + h * 128 + kc * 64 + kk]);
        iqs[kk + 0][li] = v.x; iqs[kk + 1][li] = v.y;
        iqs[kk + 2][li] = v.z; iqs[kk + 3][li] = v.w;
      }
      __syncthreads();
      #pragma unroll
      for (int kk = 0; kk < 64; ++kk) {
        float4 a = *reinterpret_cast<const float4*>(&iqs[kk][ty << 2]);
        float4 b = *reinterpret_cast<const float4*>(&iks[kc][kk][tx << 2]);
        float av[4] = {a.x, a.y, a.z, a.w};
        float bv[4] = {b.x, b.y, b.z, b.w};
        #pragma unroll
        for (int i = 0; i < 4; ++i)
          #pragma unroll
          for (int j = 0; j < 4; ++j)
            tmp[i][j] = fmaf(av[i], bv[j], tmp[i][j]);
      }
    }
    #pragma unroll
    for (int i = 0; i < 4; ++i) {
      float wv = iw[(long long)(l0 + (ty << 2) + i) * 64 + h];
      #pragma unroll
      for (int j = 0; j < 4; ++j)
        acc[i][j] += wv * fmaxf(tmp[i][j], 0.f);
    }
  }
  #pragma unroll
  for (int i = 0; i < 4; ++i) {
    int l = l0 + (ty << 2) + i;
    #pragma unroll
    for (int j = 0; j < 4; ++j) {
      int s = s0 + (tx << 2) + j;
      S[(long long)l * 1024 + s] = (s <= l) ? acc[i][j] : NEG_BIG;
    }
  }
}

// ---------------------------------------------------------------------------
// per-row top-k (radix select, f32 exact)
// ---------------------------------------------------------------------------
__global__ __launch_bounds__(256) void topk_rows(
    const float* __restrict__ S, int* __restrict__ idx_out, int* __restrict__ cnt_out)
{
  const int l = blockIdx.x;
  const int n = l + 1;
  const int k = n < 256 ? n : 256;
  if (threadIdx.x == 0) cnt_out[l] = k;
  if (k == n) {
    for (int s = threadIdx.x; s < n; s += 256) idx_out[l * 256 + s] = s;
    return;
  }
  __shared__ unsigned u[1024];
  __shared__ int hist[256];
  __shared__ unsigned sh_pref;
  __shared__ int sh_rem, cG, cE;
  const float* row = S + (long long)l * 1024;
  for (int s = threadIdx.x; s < n; s += 256) {
    unsigned b = __float_as_uint(row[s]);
    u[s] = (b & 0x80000000u) ? ~b : (b | 0x80000000u);
  }
  __syncthreads();
  unsigned prefix = 0;
  int rem = k;
  for (int pass = 0; pass < 4; ++pass) {
    const int shift = 24 - 8 * pass;
    hist[threadIdx.x] = 0;
    __syncthreads();
    const unsigned hiMask = (pass == 0) ? 0u : (0xFFFFFFFFu << (shift + 8));
    for (int s = threadIdx.x; s < n; s += 256) {
      unsigned uv = u[s];
      if ((uv & hiMask) == (prefix & hiMask))
        atomicAdd(&hist[(uv >> shift) & 255], 1);
    }
    __syncthreads();
    if (threadIdx.x == 0) {
      int cum = 0, b = 255;
      for (; b > 0; --b) { cum += hist[b]; if (cum >= rem) break; }
      if (cum < rem) cum += hist[0];
      sh_rem  = rem - (cum - hist[b]);
      sh_pref = prefix | ((unsigned)b << shift);
    }
    __syncthreads();
    prefix = sh_pref;
    rem = sh_rem;
    __syncthreads();
  }
  if (threadIdx.x == 0) { cG = 0; cE = 0; }
  __syncthreads();
  for (int s = threadIdx.x; s < n; s += 256) {
    if (u[s] > prefix) { int p = atomicAdd(&cG, 1); idx_out[l * 256 + p] = s; }
  }
  __syncthreads();
  const int base = cG;
  for (int s = threadIdx.x; s < n; s += 256) {
    if (u[s] == prefix) {
      int p = atomicAdd(&cE, 1);
      if (p < rem) idx_out[l * 256 + base + p] = s;
    }
  }
}

// ---------------------------------------------------------------------------
// qeh pe-fill: qeh[l][h][512+p] = bf16(roped q_pe)
// ---------------------------------------------------------------------------
__global__ void pe_fill(const float* __restrict__ qbuf, unsigned short* __restrict__ qeh)
{
  const int l = blockIdx.x, t = threadIdx.x;
  const int h = t >> 3, p0 = (t & 7) * 8;
  const float* src = qbuf + (long long)l * 6144 + h * 192 + 128 + p0;
  unsigned short* dst = qeh + (long long)l * 18432 + h * 576 + 512 + p0;
  #pragma unroll
  for (int i = 0; i < 8; ++i) dst[i] = f2bf(src[i]);
}

// ---------------------------------------------------------------------------
// Latent sparse attention, one block per l.
// scores S(32h x 256keys) = (q_eff||q_pe)_bf16 . gathered c_bf16 via MFMA,
// f32 softmax, f32 VALU PV over latent (512), bf16 lat_out.
// ---------------------------------------------------------------------------
__global__ __launch_bounds__(256) void latent_attn(
    const unsigned short* __restrict__ qeh,  // [1024][32][576] bf16
    const float* __restrict__ ckv,           // [1024][576] f32
    const unsigned short* __restrict__ ckv_bf,
    const int* __restrict__ tk_idx, const int* __restrict__ tk_cnt,
    unsigned short* __restrict__ lat_bf)     // [1024][32][512] bf16
{
  const int L_ = blockIdx.x;
  const int t = threadIdx.x;
  const int w = t >> 6;
  const int cnt = tk_cnt[L_];
  __shared__ int jl[256];
  __shared__ float S[32][264];
  jl[t] = (t < cnt) ? tk_idx[L_ * 256 + t] : 0;
  __syncthreads();

  // scores via MFMA: wave w owns key-cols [w*64, w*64+64)
  f32x4 acc[2][4] = {};
  int jr[4];
  #pragma unroll
  for (int nj = 0; nj < 4; ++nj) jr[nj] = jl[w * 64 + nj * 16 + (t & 15)];
  const unsigned short* ab = qeh + (long long)L_ * 18432;
  const int ko_lane = ((t >> 4) & 3) * 8;
  for (int ks = 0; ks < 18; ++ks) {
    const int k0 = ks * 32 + ko_lane;
    bf16x8 a0 = *reinterpret_cast<const bf16x8*>(ab + (t & 15) * 576 + k0);
    bf16x8 a1 = *reinterpret_cast<const bf16x8*>(ab + ((t & 15) + 16) * 576 + k0);
    #pragma unroll
    for (int nj = 0; nj < 4; ++nj) {
      bf16x8 bfr = *reinterpret_cast<const bf16x8*>(ckv_bf + (long long)jr[nj] * 576 + k0);
      acc[0][nj] = __builtin_amdgcn_mfma_f32_16x16x32_bf16(a0, bfr, acc[0][nj], 0, 0, 0);
      acc[1][nj] = __builtin_amdgcn_mfma_f32_16x16x32_bf16(a1, bfr, acc[1][nj], 0, 0, 0);
    }
  }
  const int rbase = ((t >> 4) & 3) * 4;
  #pragma unroll
  for (int mi = 0; mi < 2; ++mi)
    #pragma unroll
    for (int nj = 0; nj < 4; ++nj) {
      const int col = w * 64 + nj * 16 + (t & 15);
      #pragma unroll
      for (int r = 0; r < 4; ++r)
        S[mi * 16 + rbase + r][col] = (col < cnt) ? acc[mi][nj][r] * SCALE_ATTN : NEG_BIG;
    }
  __syncthreads();

  // softmax: 8 lanes per head-row
  {
    const int row = t >> 3, lane = t & 7;
    float mx = NEG_BIG;
    for (int j = lane; j < 256; j += 8) mx = fmaxf(mx, S[row][j]);
    #pragma unroll
    for (int o = 1; o < 8; o <<= 1) mx = fmaxf(mx, __shfl_xor(mx, o));
    float sum = 0.f;
    for (int j = lane; j < 256; j += 8) {
      float e = __expf(S[row][j] - mx);
      S[row][j] = e;
      sum += e;
    }
    #pragma unroll
    for (int o = 1; o < 8; o <<= 1) sum += __shfl_xor(sum, o);
    const float inv = 1.f / sum;
    for (int j = lane; j < 256; j += 8) S[row][j] *= inv;
  }
  __syncthreads();

  // PV in latent space (f32): thread owns d4 = t&127 (4 dims), 16 heads
  const int d4 = t & 127, h0 = (t >> 7) * 16;
  float4 o[16];
  #pragma unroll
  for (int i = 0; i < 16; ++i) o[i] = make_float4(0.f, 0.f, 0.f, 0.f);
  for (int j = 0; j < cnt; ++j) {
    const int jj = jl[j];
    const float4 c4 = *reinterpret_cast<const float4*>(ckv + (long long)jj * 576 + d4 * 4);
    #pragma unroll
    for (int i = 0; i < 16; ++i) {
      const float p = S[h0 + i][j];
      o[i].x = fmaf(p, c4.x, o[i].x);
      o[i].y = fmaf(p, c4.y, o[i].y);
      o[i].z = fmaf(p, c4.z, o[i].z);
      o[i].w = fmaf(p, c4.w, o[i].w);
    }
  }
  unsigned short* ob = lat_bf + (long long)L_ * 16384 + d4 * 4;
  #pragma unroll
  for (int i = 0; i < 16; ++i) {
    ushort4 pk;
    pk.x = f2bf(o[i].x); pk.y = f2bf(o[i].y); pk.z = f2bf(o[i].z); pk.w = f2bf(o[i].w);
    *reinterpret_cast<ushort4*>(ob + (h0 + i) * 512) = pk;
  }
}

// ---------------------------------------------------------------------------
extern "C" void kernel_launch(void* const* d_in, const int* in_sizes, int n_in,
                              void* d_out, int out_size, void* d_ws, size_t ws_size,
                              hipStream_t stream)
{
  const float* x        = (const float*)d_in[0];
  const float* W_qa     = (const float*)d_in[2];
  const float* qa_ln_w  = (const float*)d_in[3];
  const float* W_qb     = (const float*)d_in[4];
  const float* W_kva    = (const float*)d_in[5];
  const float* kva_ln_w = (const float*)d_in[6];
  const float* W_eq     = (const float*)d_in[7];   // [32][512][128]
  const float* W_uo     = (const float*)d_in[8];   // [32][128][512]
  const float* W_o      = (const float*)d_in[9];   // [4096][4096]
  const float* idx_wqb  = (const float*)d_in[10];  // [8192][1536]
  const float* idx_wk   = (const float*)d_in[11];  // [128][4096]
  const float* idx_klnw = (const float*)d_in[12];
  const float* idx_klnb = (const float*)d_in[13];
  const float* idx_wprj = (const float*)d_in[14];  // [64][4096]
  float* out = (float*)d_out;

  char* W = (char*)d_ws;
  // region 0: qr f32 + qr_bf  (later aliased by attn_bf)
  float*          qr      = (float*)(W + 0);                  // 6,291,456 B
  unsigned short* qr_bf   = (unsigned short*)(W + 6291456);   // 3,145,728 B
  unsigned short* attn_bf = (unsigned short*)(W + 0);         // 8,388,608 B (alias, late)
  // region U1: qbuf f32 + qbuf_bf  (later aliased by lat_bf)
  const size_t U1 = 9437184;
  float*          qbuf    = (float*)(W + U1);                  // 25,165,824
  unsigned short* qbuf_bf = (unsigned short*)(W + U1 + 25165824); // 12,582,912
  unsigned short* lat_bf  = (unsigned short*)(W + U1);         // 33,554,432 (alias, late)
  // region U2: ckv
  const size_t U2 = U1 + 37748736;
  float*          ckv     = (float*)(W + U2);                  // 2,359,296
  unsigned short* ckv_bf  = (unsigned short*)(W + U2 + 2359296); // 1,179,648
  // region U3: qa-partials -> iqbuf -> qeh_bf -> W_o_bf (sequential lifetimes)
  const size_t U3 = U2 + 3538944;
  float*          part_qa = (float*)(W + U3);                  // 25,165,824
  float*          iqbuf   = (float*)(W + U3);                  // 33,554,432
  unsigned short* qeh_bf  = (unsigned short*)(W + U3);         // 37,748,736
  unsigned short* W_o_bf  = (unsigned short*)(W + U3);         // 33,554,432
  // region U4: indexer smalls
  const size_t U4 = U3 + 37748736;
  float* ikbuf   = (float*)(W + U4);
  float* iwbuf   = (float*)(W + U4 + 524288);
  float* iscores = (float*)(W + U4 + 786432);
  int*   tk_idx  = (int*)(W + U4 + 4980736);
  int*   tk_cnt  = (int*)(W + U4 + 6029312);
  // region U5: wk/wproj partials -> W_qb_bf -> W_eq_bf + W_uo_bf
  const size_t U5 = U4 + 6033408;
  float*          part_wk = (float*)(W + U5);                  // 4,194,304
  float*          part_wp = (float*)(W + U5 + 4194304);        // 4,194,304
  unsigned short* W_qb_bf = (unsigned short*)(W + U5);         // 18,874,368
  unsigned short* W_eq_bf = (unsigned short*)(W + U5);         // 4,194,304
  unsigned short* W_uo_bf = (unsigned short*)(W + U5 + 4194304); // 4,194,304

  // 1) qr = rmsnorm(x @ W_qa.T)  -- f32, splitK=4 (128-tile)
  gemm_f32_128<<<dim3(12, 8, 4), 256, 0, stream>>>(
      x, W_qa, part_qa, 1024, 4096, 4096, 1536, 1024, 1024, 1024LL * 1536, 1.f);
  reduce_sk<<<(393216 + 255) / 256, 256, 0, stream>>>(part_qa, qr, 393216, 4);
  rmsnorm_rows<<<1024, 256, 0, stream>>>(qr, qa_ln_w, 1536, 1536, 1e-6f);

  // 2) ckv = x @ W_kva.T ; rmsnorm ; rope k_pe
  gemm_f32<true><<<dim3(9, 16, 1), 256, 0, stream>>>(
      x, W_kva, ckv, 1024, 576, 4096, 4096, 4096, 576, 0, 0, 0, 1.f);
  rmsnorm_rows<<<1024, 256, 0, stream>>>(ckv, kva_ln_w, 512, 576, 1e-6f);
  rope_apply<<<dim3(1024, 1), 32, 0, stream>>>(ckv, 576, 0, 512);

  // 3) ik = rope(layernorm(x @ idx_wk.T))  -- splitK=8
  gemm_f32<true><<<dim3(2, 16, 8), 256, 0, stream>>>(
      x, idx_wk, part_wk, 1024, 128, 512, 4096, 4096, 128, 512, 512, 131072, 1.f);
  reduce_sk<<<(32768 + 255) / 256, 256, 0, stream>>>(part_wk, ikbuf, 32768, 8);
  layernorm_rows<<<1024, 128, 0, stream>>>(ikbuf, idx_klnw, idx_klnb, 1e-5f);
  rope_apply<<<dim3(1024, 1), 32, 0, stream>>>(ikbuf, 128, 0, 0);

  // 4) iw = x @ idx_wproj.T * scale  -- splitK=16
  gemm_f32<true><<<dim3(1, 16, 16), 256, 0, stream>>>(
      x, idx_wprj, part_wp, 1024, 64, 256, 4096, 4096, 64, 256, 256, 65536, IW_SCALE);
  reduce_sk<<<(16384 + 255) / 256, 256, 0, stream>>>(part_wp, iwbuf, 16384, 16);

  // 5) q = (qr_bf @ W_qb_bf.T) [bf16 MFMA] ; rope q_pe
  f2bf_k<<<(2359296 + 255) / 256, 256, 0, stream>>>(W_qb, W_qb_bf, 2359296);
  f2bf_k<<<(393216 + 255) / 256, 256, 0, stream>>>(qr, qr_bf, 393216);
  gemm_bf16nt<false><<<dim3(48, 8, 1), 256, 0, stream>>>(
      qr_bf, W_qb_bf, qbuf, 1536, 1536, 1536, 6144, 0, 0, 0);
  rope_apply<<<dim3(1024, 32), 32, 0, stream>>>(qbuf, 6144, 192, 128);

  // 6) iq = qr @ idx_wqb.T (f32, 128-tile) ; rope
  gemm_f32_128<<<dim3(64, 8, 1), 256, 0, stream>>>(
      qr, idx_wqb, iqbuf, 1536, 1536, 1536, 8192, 0, 0, 0, 1.f);
  rope_apply<<<dim3(1024, 64), 32, 0, stream>>>(iqbuf, 8192, 128, 0);

  // 7) indexer scores + topk (f32 exact)
  indexer_scores<<<dim3(16, 16), 256, 0, stream>>>(iqbuf, ikbuf, iwbuf, iscores);
  topk_rows<<<1024, 256, 0, stream>>>(iscores, tk_idx, tk_cnt);

  // 8) converts for attention path (iqbuf now dead -> U3 becomes qeh_bf)
  f2bf_k<<<(1572864 + 255) / 256, 256, 0, stream>>>(qbuf, qbuf_bf, 1572864);
  f2bf_k<<<(147456 + 255) / 256, 256, 0, stream>>>(ckv, ckv_bf, 147456);
  f2bf_k<<<(524288 + 255) / 256, 256, 0, stream>>>(W_eq, W_eq_bf, 524288);
  f2bf_k<<<(524288 + 255) / 256, 256, 0, stream>>>(W_uo, W_uo_bf, 524288);

  // 9) q_eff[l,h,:512] = q_nope . W_eq[h]^T  (batched bf16) ; append roped pe
  gemm_bf16nt<true><<<dim3(4, 8, 32), 256, 0, stream>>>(
      qbuf_bf, W_eq_bf, qeh_bf, 128, 6144, 128, 18432, 192, 65536, 576);
  pe_fill<<<1024, 256, 0, stream>>>(qbuf, qeh_bf);

  // 10) latent sparse attention
  latent_attn<<<1024, 256, 0, stream>>>(qeh_bf, ckv, ckv_bf, tk_idx, tk_cnt, lat_bf);

  // 11) out_head = lat_out @ W_uo[h].T (batched bf16 -> bf16)
  gemm_bf16nt<true><<<dim3(1, 8, 32), 256, 0, stream>>>(
      lat_bf, W_uo_bf, attn_bf, 512, 16384, 512, 4096, 512, 65536, 128);

  // 12) out = attn @ W_o.T (bf16 -> f32), W_o_bf reuses U3 (qeh dead)
  f2bf_k<<<(4194304 + 255) / 256, 256, 0, stream>>>(W_o, W_o_bf, 4194304);
  gemm_bf16nt<false><<<dim3(32, 8, 1), 256, 0, stream>>>(
      attn_bf, W_o_bf, out, 4096, 4096, 4096, 4096, 0, 0, 0);
}

// Round 4
// 1492.075 us; speedup vs baseline: 2.4458x; 1.2547x over previous
//
#include <hip/hip_runtime.h>
#include <math.h>

#define NEG_BIG -3.402823466e38f
#define SCALE_ATTN 0.07216878364870323f   /* 192^-0.5 */
#define IW_SCALE   0.011048543456039806f  /* (64*128)^-0.5 */

typedef __attribute__((ext_vector_type(8))) short  bf16x8;
typedef __attribute__((ext_vector_type(4))) float  f32x4;

__device__ __forceinline__ unsigned short f2bf(float f) {
  unsigned u = __float_as_uint(f);
  unsigned r = (u + 0x7FFFu + ((u >> 16) & 1u)) >> 16;
  return (unsigned short)r;
}
__device__ __forceinline__ float bf2f(unsigned short h) {
  return __uint_as_float(((unsigned)h) << 16);
}
__device__ __forceinline__ void split3(float x, unsigned short& h, unsigned short& m,
                                       unsigned short& l) {
  h = f2bf(x);
  float r = x - bf2f(h);
  m = f2bf(r);
  float r2 = r - bf2f(m);
  l = f2bf(r2);
}

// ---------------------------------------------------------------------------
// f32 tiled GEMM 64x64x16 (NT / NN), batched/split-K via sA/sB/sC.
// ---------------------------------------------------------------------------
template<bool BT>
__global__ __launch_bounds__(256) void gemm_f32(
    const float* __restrict__ A, const float* __restrict__ B, float* __restrict__ C,
    int M, int N, int K, int lda, int ldb, int ldc,
    long long sA, long long sB, long long sC, float alpha)
{
  __shared__ float As[16][68];
  __shared__ float Bs[16][68];
  A += (long long)blockIdx.z * sA;
  B += (long long)blockIdx.z * sB;
  C += (long long)blockIdx.z * sC;
  const int m0 = blockIdx.y * 64;
  const int n0 = blockIdx.x * 64;
  const int t  = threadIdx.x;
  const int tx = t & 15, ty = t >> 4;
  float acc[4][4] = {};
  for (int k0 = 0; k0 < K; k0 += 16) {
    {
      const int m  = t >> 2;
      const int k4 = (t & 3) << 2;
      float4 v = *reinterpret_cast<const float4*>(&A[(long long)(m0 + m) * lda + k0 + k4]);
      As[k4 + 0][m] = v.x; As[k4 + 1][m] = v.y; As[k4 + 2][m] = v.z; As[k4 + 3][m] = v.w;
    }
    if (BT) {
      const int n  = t >> 2;
      const int k4 = (t & 3) << 2;
      float4 v = *reinterpret_cast<const float4*>(&B[(long long)(n0 + n) * ldb + k0 + k4]);
      Bs[k4 + 0][n] = v.x; Bs[k4 + 1][n] = v.y; Bs[k4 + 2][n] = v.z; Bs[k4 + 3][n] = v.w;
    } else {
      const int k  = t >> 4;
      const int n4 = (t & 15) << 2;
      float4 v = *reinterpret_cast<const float4*>(&B[(long long)(k0 + k) * ldb + n0 + n4]);
      *reinterpret_cast<float4*>(&Bs[k][n4]) = v;
    }
    __syncthreads();
    #pragma unroll
    for (int kk = 0; kk < 16; ++kk) {
      float4 a = *reinterpret_cast<const float4*>(&As[kk][ty << 2]);
      float4 b = *reinterpret_cast<const float4*>(&Bs[kk][tx << 2]);
      float av[4] = {a.x, a.y, a.z, a.w};
      float bv[4] = {b.x, b.y, b.z, b.w};
      #pragma unroll
      for (int i = 0; i < 4; ++i)
        #pragma unroll
        for (int j = 0; j < 4; ++j)
          acc[i][j] = fmaf(av[i], bv[j], acc[i][j]);
    }
    __syncthreads();
  }
  #pragma unroll
  for (int i = 0; i < 4; ++i) {
    float4 v = make_float4(acc[i][0] * alpha, acc[i][1] * alpha,
                           acc[i][2] * alpha, acc[i][3] * alpha);
    *reinterpret_cast<float4*>(&C[(long long)(m0 + (ty << 2) + i) * ldc + n0 + (tx << 2)]) = v;
  }
}

// ---------------------------------------------------------------------------
// f32 tiled GEMM 128x128x16 NT, 8x8 acc per thread. splitK via strides.
// ---------------------------------------------------------------------------
__global__ __launch_bounds__(256) void gemm_f32_128(
    const float* __restrict__ A, const float* __restrict__ B, float* __restrict__ C,
    int K, int lda, int ldb, int ldc,
    long long sA, long long sB, long long sC, float alpha)
{
  __shared__ float As[16][132];
  __shared__ float Bs[16][132];
  A += (long long)blockIdx.z * sA;
  B += (long long)blockIdx.z * sB;
  C += (long long)blockIdx.z * sC;
  const int m0 = blockIdx.y * 128, n0 = blockIdx.x * 128;
  const int t = threadIdx.x;
  const int tx = t & 15, ty = t >> 4;
  float acc[8][8] = {};
  for (int k0 = 0; k0 < K; k0 += 16) {
    #pragma unroll
    for (int c = 0; c < 2; ++c) {
      const int idx = c * 256 + t;
      const int row = idx >> 2;
      const int k4 = (idx & 3) << 2;
      float4 va = *reinterpret_cast<const float4*>(&A[(long long)(m0 + row) * lda + k0 + k4]);
      As[k4+0][row]=va.x; As[k4+1][row]=va.y; As[k4+2][row]=va.z; As[k4+3][row]=va.w;
      float4 vb = *reinterpret_cast<const float4*>(&B[(long long)(n0 + row) * ldb + k0 + k4]);
      Bs[k4+0][row]=vb.x; Bs[k4+1][row]=vb.y; Bs[k4+2][row]=vb.z; Bs[k4+3][row]=vb.w;
    }
    __syncthreads();
    #pragma unroll
    for (int kk = 0; kk < 16; ++kk) {
      float a[8], b[8];
      *(float4*)&a[0] = *(const float4*)&As[kk][ty * 8];
      *(float4*)&a[4] = *(const float4*)&As[kk][ty * 8 + 4];
      *(float4*)&b[0] = *(const float4*)&Bs[kk][tx * 8];
      *(float4*)&b[4] = *(const float4*)&Bs[kk][tx * 8 + 4];
      #pragma unroll
      for (int i = 0; i < 8; ++i)
        #pragma unroll
        for (int j = 0; j < 8; ++j)
          acc[i][j] = fmaf(a[i], b[j], acc[i][j]);
    }
    __syncthreads();
  }
  #pragma unroll
  for (int i = 0; i < 8; ++i) {
    const long long row = (long long)(m0 + ty * 8 + i) * ldc + n0 + tx * 8;
    float4 v0 = make_float4(acc[i][0]*alpha, acc[i][1]*alpha, acc[i][2]*alpha, acc[i][3]*alpha);
    float4 v1 = make_float4(acc[i][4]*alpha, acc[i][5]*alpha, acc[i][6]*alpha, acc[i][7]*alpha);
    *reinterpret_cast<float4*>(&C[row])     = v0;
    *reinterpret_cast<float4*>(&C[row + 4]) = v1;
  }
}

// ---------------------------------------------------------------------------
// iq GEMM: qr[1024][1536] @ idx_wqb[8192][1536]^T with fused traditional RoPE
// (first 64 dims of each 128-dim head) and 3-level bf16 split epilogue.
// grid (64, 8). Same core as gemm_f32_128.
// ---------------------------------------------------------------------------
__global__ __launch_bounds__(256) void gemm_iq(
    const float* __restrict__ A, const float* __restrict__ B,
    unsigned short* __restrict__ Oh, unsigned short* __restrict__ Om,
    unsigned short* __restrict__ Ol)
{
  __shared__ float As[16][132];
  __shared__ float Bs[16][132];
  const int m0 = blockIdx.y * 128, n0 = blockIdx.x * 128;
  const int t = threadIdx.x;
  const int tx = t & 15, ty = t >> 4;
  float acc[8][8] = {};
  for (int k0 = 0; k0 < 1536; k0 += 16) {
    #pragma unroll
    for (int c = 0; c < 2; ++c) {
      const int idx = c * 256 + t;
      const int row = idx >> 2;
      const int k4 = (idx & 3) << 2;
      float4 va = *reinterpret_cast<const float4*>(&A[(long long)(m0 + row) * 1536 + k0 + k4]);
      As[k4+0][row]=va.x; As[k4+1][row]=va.y; As[k4+2][row]=va.z; As[k4+3][row]=va.w;
      float4 vb = *reinterpret_cast<const float4*>(&B[(long long)(n0 + row) * 1536 + k0 + k4]);
      Bs[k4+0][row]=vb.x; Bs[k4+1][row]=vb.y; Bs[k4+2][row]=vb.z; Bs[k4+3][row]=vb.w;
    }
    __syncthreads();
    #pragma unroll
    for (int kk = 0; kk < 16; ++kk) {
      float a[8], b[8];
      *(float4*)&a[0] = *(const float4*)&As[kk][ty * 8];
      *(float4*)&a[4] = *(const float4*)&As[kk][ty * 8 + 4];
      *(float4*)&b[0] = *(const float4*)&Bs[kk][tx * 8];
      *(float4*)&b[4] = *(const float4*)&Bs[kk][tx * 8 + 4];
      #pragma unroll
      for (int i = 0; i < 8; ++i)
        #pragma unroll
        for (int j = 0; j < 8; ++j)
          acc[i][j] = fmaf(a[i], b[j], acc[i][j]);
    }
    __syncthreads();
  }
  const int c0 = n0 + tx * 8;
  const int d0 = c0 & 127;              // dim within 128-dim indexer head
  float invs[4];
  if (d0 < 64) {
    #pragma unroll
    for (int j = 0; j < 4; ++j) {
      int pi = (d0 >> 1) + j;
      invs[j] = powf(10000.f, -(float)(2 * pi) / 64.f);
    }
  }
  #pragma unroll
  for (int i = 0; i < 8; ++i) {
    const int row = m0 + ty * 8 + i;
    float v[8];
    if (d0 < 64) {
      #pragma unroll
      for (int j = 0; j < 4; ++j) {
        float ang = (float)row * invs[j];
        float cc = cosf(ang), ss = sinf(ang);
        float x1 = acc[i][2*j], x2 = acc[i][2*j+1];
        v[2*j]   = x1 * cc - x2 * ss;
        v[2*j+1] = x1 * ss + x2 * cc;
      }
    } else {
      #pragma unroll
      for (int j = 0; j < 8; ++j) v[j] = acc[i][j];
    }
    ushort4 H[2], M[2], L[2];
    #pragma unroll
    for (int q = 0; q < 2; ++q) {
      unsigned short hh[4], mm[4], ll[4];
      #pragma unroll
      for (int j = 0; j < 4; ++j) split3(v[q*4+j], hh[j], mm[j], ll[j]);
      H[q] = make_ushort4(hh[0], hh[1], hh[2], hh[3]);
      M[q] = make_ushort4(mm[0], mm[1], mm[2], mm[3]);
      L[q] = make_ushort4(ll[0], ll[1], ll[2], ll[3]);
    }
    const long long off = (long long)row * 8192 + c0;
    *reinterpret_cast<ushort4*>(&Oh[off])     = H[0];
    *reinterpret_cast<ushort4*>(&Oh[off + 4]) = H[1];
    *reinterpret_cast<ushort4*>(&Om[off])     = M[0];
    *reinterpret_cast<ushort4*>(&Om[off + 4]) = M[1];
    *reinterpret_cast<ushort4*>(&Ol[off])     = L[0];
    *reinterpret_cast<ushort4*>(&Ol[off + 4]) = L[1];
  }
}

// ---------------------------------------------------------------------------
// split-K reduce / converts
// ---------------------------------------------------------------------------
__global__ void reduce_sk(const float* __restrict__ part, float* __restrict__ out,
                          int n4, int S)
{
  int i = blockIdx.x * 256 + threadIdx.x;
  if (i >= n4) return;
  const float4* p = (const float4*)part;
  float4 s = p[i];
  for (int z = 1; z < S; ++z) {
    float4 v = p[(long long)z * n4 + i];
    s.x += v.x; s.y += v.y; s.z += v.z; s.w += v.w;
  }
  ((float4*)out)[i] = s;
}

__global__ void f2bf_k(const float* __restrict__ in, unsigned short* __restrict__ out, int n4)
{
  int i = blockIdx.x * 256 + threadIdx.x;
  if (i >= n4) return;
  float4 v = ((const float4*)in)[i];
  ushort4 o;
  o.x = f2bf(v.x); o.y = f2bf(v.y); o.z = f2bf(v.z); o.w = f2bf(v.w);
  ((ushort4*)out)[i] = o;
}

__global__ void split3_k(const float* __restrict__ in, unsigned short* __restrict__ oh,
                         unsigned short* __restrict__ om, unsigned short* __restrict__ ol,
                         int n4)
{
  int i = blockIdx.x * 256 + threadIdx.x;
  if (i >= n4) return;
  float4 v = ((const float4*)in)[i];
  float vv[4] = {v.x, v.y, v.z, v.w};
  unsigned short hh[4], mm[4], ll[4];
  #pragma unroll
  for (int j = 0; j < 4; ++j) split3(vv[j], hh[j], mm[j], ll[j]);
  ((ushort4*)oh)[i] = make_ushort4(hh[0], hh[1], hh[2], hh[3]);
  ((ushort4*)om)[i] = make_ushort4(mm[0], mm[1], mm[2], mm[3]);
  ((ushort4*)ol)[i] = make_ushort4(ll[0], ll[1], ll[2], ll[3]);
}

// ---------------------------------------------------------------------------
// bf16 NT GEMM: C = A(MxK) * B(NxK)^T, 128x128 tile, BK=64, dbuf global_load_lds.
// ROPE_Q: apply traditional RoPE to cols with (col%192)>=128 (q_pe) in epilogue.
// ---------------------------------------------------------------------------
template<bool STORE_BF16, bool ROPE_Q>
__global__ __launch_bounds__(256) void gemm_bf16nt(
    const unsigned short* __restrict__ Ag, const unsigned short* __restrict__ Bg,
    void* __restrict__ Cout,
    int K, int lda, int ldb, int ldc,
    long long sA, long long sB, long long sC)
{
  __shared__ unsigned short As[2][128 * 64];
  __shared__ unsigned short Bs[2][128 * 64];
  Ag += (long long)blockIdx.z * sA;
  Bg += (long long)blockIdx.z * sB;
  const long long cz = (long long)blockIdx.z * sC;
  const int m0 = blockIdx.y * 128, n0 = blockIdx.x * 128;
  const int t = threadIdx.x;
  const int wr = (t >> 7) & 1;
  const int wc = (t >> 6) & 1;
  f32x4 acc[4][4] = {};

#define STAGE_TILE(buf, kt) do {                                              \
    const int k0s = (kt) * 64;                                                \
    _Pragma("unroll")                                                         \
    for (int c = 0; c < 4; ++c) {                                             \
      const int idx = c * 256 + t;                                            \
      const int row = idx >> 3;                                               \
      const int col = (idx & 7) << 3;                                         \
      const unsigned short* gA = Ag + (long long)(m0 + row) * lda + k0s + col;\
      const unsigned short* gB = Bg + (long long)(n0 + row) * ldb + k0s + col;\
      __builtin_amdgcn_global_load_lds(                                       \
          (const __attribute__((address_space(1))) void*)gA,                  \
          (__attribute__((address_space(3))) void*)(&As[buf][(c * 256 + (t & 192)) << 3]), \
          16, 0, 0);                                                          \
      __builtin_amdgcn_global_load_lds(                                       \
          (const __attribute__((address_space(1))) void*)gB,                  \
          (__attribute__((address_space(3))) void*)(&Bs[buf][(c * 256 + (t & 192)) << 3]), \
          16, 0, 0);                                                          \
    }                                                                         \
  } while (0)

  const int nt = K >> 6;
  STAGE_TILE(0, 0);
  __syncthreads();
  int cur = 0;
  for (int kt = 0; kt < nt; ++kt) {
    if (kt + 1 < nt) STAGE_TILE(cur ^ 1, kt + 1);
    #pragma unroll
    for (int kk = 0; kk < 2; ++kk) {
      const int ko = kk * 32 + ((t >> 4) & 3) * 8;
      bf16x8 af[4], bfr[4];
      #pragma unroll
      for (int mi = 0; mi < 4; ++mi)
        af[mi] = *reinterpret_cast<const bf16x8*>(&As[cur][(wr*64 + mi*16 + (t & 15)) * 64 + ko]);
      #pragma unroll
      for (int nj = 0; nj < 4; ++nj)
        bfr[nj] = *reinterpret_cast<const bf16x8*>(&Bs[cur][(wc*64 + nj*16 + (t & 15)) * 64 + ko]);
      #pragma unroll
      for (int mi = 0; mi < 4; ++mi)
        #pragma unroll
        for (int nj = 0; nj < 4; ++nj)
          acc[mi][nj] = __builtin_amdgcn_mfma_f32_16x16x32_bf16(af[mi], bfr[nj], acc[mi][nj], 0, 0, 0);
    }
    __syncthreads();
    cur ^= 1;
  }
#undef STAGE_TILE

  const int r0 = ((t >> 4) & 3) << 2;
  #pragma unroll
  for (int mi = 0; mi < 4; ++mi)
    #pragma unroll
    for (int nj = 0; nj < 4; ++nj) {
      const int col = n0 + wc * 64 + nj * 16 + (t & 15);
      #pragma unroll
      for (int r = 0; r < 4; ++r) {
        const int row = m0 + wr * 64 + mi * 16 + r0 + r;
        float val = acc[mi][nj][r];
        if constexpr (ROPE_Q) {
          float partner = __shfl_xor(val, 1);
          const int hd = col % 192;
          if (hd >= 128) {
            int pi = (hd - 128) >> 1;
            float inv = powf(10000.f, -(float)(2 * pi) / 64.f);
            float ang = (float)row * inv;
            float cc = cosf(ang), ss = sinf(ang);
            val = (t & 1) ? (partner * ss + val * cc) : (val * cc - partner * ss);
          }
        }
        const long long off = cz + (long long)row * ldc + col;
        if constexpr (STORE_BF16)
          ((unsigned short*)Cout)[off] = f2bf(val);
        else
          ((float*)Cout)[off] = val;
      }
    }
}

// ---------------------------------------------------------------------------
__global__ __launch_bounds__(256) void rmsnorm_rows(
    float* __restrict__ y, const float* __restrict__ w, int N, int ld, float eps)
{
  const int row = blockIdx.x;
  float* p = y + (long long)row * ld;
  float ss = 0.f;
  for (int i = threadIdx.x; i < N; i += 256) { float v = p[i]; ss += v * v; }
  __shared__ float red[4];
  #pragma unroll
  for (int o = 32; o; o >>= 1) ss += __shfl_down(ss, o);
  if ((threadIdx.x & 63) == 0) red[threadIdx.x >> 6] = ss;
  __syncthreads();
  if (threadIdx.x == 0) {
    float s = red[0] + red[1] + red[2] + red[3];
    red[0] = rsqrtf(s / (float)N + eps);
  }
  __syncthreads();
  const float sc = red[0];
  for (int i = threadIdx.x; i < N; i += 256) p[i] = p[i] * sc * w[i];
}

__global__ __launch_bounds__(128) void layernorm_rows(
    float* __restrict__ y, const float* __restrict__ w, const float* __restrict__ b,
    float eps)
{
  const int row = blockIdx.x;
  float* p = y + (long long)row * 128;
  float v = p[threadIdx.x];
  __shared__ float red[2];
  float s = v;
  #pragma unroll
  for (int o = 32; o; o >>= 1) s += __shfl_down(s, o);
  if ((threadIdx.x & 63) == 0) red[threadIdx.x >> 6] = s;
  __syncthreads();
  const float mu = (red[0] + red[1]) * (1.f / 128.f);
  const float d = v - mu;
  float s2 = d * d;
  #pragma unroll
  for (int o = 32; o; o >>= 1) s2 += __shfl_down(s2, o);
  __syncthreads();
  if ((threadIdx.x & 63) == 0) red[threadIdx.x >> 6] = s2;
  __syncthreads();
  const float var = (red[0] + red[1]) * (1.f / 128.f);
  p[threadIdx.x] = d * rsqrtf(var + eps) * w[threadIdx.x] + b[threadIdx.x];
}

__global__ void rope_apply(float* __restrict__ buf, int rowStride, int headStride, int dOff)
{
  const int l = blockIdx.x, h = blockIdx.y, i = threadIdx.x;
  const float inv = powf(10000.f, -(float)(2 * i) / 64.f);
  const float ang = (float)l * inv;
  const float c = cosf(ang), s = sinf(ang);
  float* pp = buf + (long long)l * rowStride + (long long)h * headStride + dOff + 2 * i;
  const float x1 = pp[0], x2 = pp[1];
  pp[0] = x1 * c - x2 * s;
  pp[1] = x1 * s + x2 * c;
}

// ---------------------------------------------------------------------------
// Indexer scores via 6-term split-bf16 MFMA (f32-equivalent precision).
// S[l][s] = sum_h iw[l][h] * relu(iq[l][h][:] . ik[s][:]) over 128 dims.
// 64x64 tile per block, lower-triangular grid; 4 waves = 2x2 quadrants.
// iq/ik staged via global_load_lds with XOR-swizzled source (conflict-free
// ds_read_b128); ik fragments hoisted to registers (head-invariant).
// ---------------------------------------------------------------------------
__global__ __launch_bounds__(256, 1) void indexer_mfma(
    const unsigned short* __restrict__ iqh, const unsigned short* __restrict__ iqm,
    const unsigned short* __restrict__ iql,
    const unsigned short* __restrict__ ikh, const unsigned short* __restrict__ ikm,
    const unsigned short* __restrict__ ikl,
    const float* __restrict__ iw, float* __restrict__ S)
{
  const int lb = blockIdx.y, sb = blockIdx.x;
  if (sb > lb) return;
  __shared__ unsigned short IK[3][64 * 128];
  __shared__ unsigned short IQ[2][3][64 * 128];
  const int t = threadIdx.x;
  const int l0 = lb * 64, s0 = sb * 64;
  const int wr = (t >> 7) & 1, wc = (t >> 6) & 1;
  const int g = (t >> 4) & 3;

  const unsigned short* ikL[3] = {ikh, ikm, ikl};
  #pragma unroll
  for (int lvl = 0; lvl < 3; ++lvl)
    #pragma unroll
    for (int c = 0; c < 4; ++c) {
      const int cl = c * 256 + t;
      const int row = cl >> 4, cir = cl & 15;
      const int rc = cir ^ (row & 7);
      const unsigned short* src = ikL[lvl] + (long long)(s0 + row) * 128 + rc * 8;
      __builtin_amdgcn_global_load_lds(
          (const __attribute__((address_space(1))) void*)src,
          (__attribute__((address_space(3))) void*)(&IK[lvl][(c * 256 + (t & 192)) * 8]),
          16, 0, 0);
    }
  const unsigned short* iqL[3] = {iqh, iqm, iql};
#define STAGE_IQ(buf, hh) do {                                                \
    _Pragma("unroll")                                                         \
    for (int lvl = 0; lvl < 3; ++lvl)                                         \
      _Pragma("unroll")                                                       \
      for (int c = 0; c < 4; ++c) {                                           \
        const int cl = c * 256 + t;                                           \
        const int row = cl >> 4, cir = cl & 15;                               \
        const int rc = cir ^ (row & 7);                                       \
        const unsigned short* src = iqL[lvl] +                                \
            (long long)(l0 + row) * 8192 + (hh) * 128 + rc * 8;               \
        __builtin_amdgcn_global_load_lds(                                     \
            (const __attribute__((address_space(1))) void*)src,               \
            (__attribute__((address_space(3))) void*)(&IQ[buf][lvl][(c * 256 + (t & 192)) * 8]), \
            16, 0, 0);                                                        \
      }                                                                       \
  } while (0)

  STAGE_IQ(0, 0);
  __syncthreads();

  // hoist ik fragments (head-invariant): [nj][kk][lvl]
  bf16x8 Bf[2][4][3];
  #pragma unroll
  for (int nj = 0; nj < 2; ++nj)
    #pragma unroll
    for (int kk = 0; kk < 4; ++kk) {
      const int row = wc * 32 + nj * 16 + (t & 15);
      const int ci = (kk * 4 + g) ^ (row & 7);
      const int off = row * 128 + ci * 8;
      #pragma unroll
      for (int lvl = 0; lvl < 3; ++lvl)
        Bf[nj][kk][lvl] = *reinterpret_cast<const bf16x8*>(&IK[lvl][off]);
    }

  f32x4 accS[2][2] = {};
  int cur = 0;
  for (int h = 0; h < 64; ++h) {
    if (h + 1 < 64) STAGE_IQ(cur ^ 1, h + 1);
    f32x4 accP[2][2] = {};
    #pragma unroll
    for (int kk = 0; kk < 4; ++kk) {
      bf16x8 Af[2][3];
      #pragma unroll
      for (int mi = 0; mi < 2; ++mi) {
        const int row = wr * 32 + mi * 16 + (t & 15);
        const int ci = (kk * 4 + g) ^ (row & 7);
        const int off = row * 128 + ci * 8;
        #pragma unroll
        for (int lvl = 0; lvl < 3; ++lvl)
          Af[mi][lvl] = *reinterpret_cast<const bf16x8*>(&IQ[cur][lvl][off]);
      }
      #pragma unroll
      for (int mi = 0; mi < 2; ++mi)
        #pragma unroll
        for (int nj = 0; nj < 2; ++nj) {
          f32x4 a = accP[mi][nj];
          a = __builtin_amdgcn_mfma_f32_16x16x32_bf16(Af[mi][0], Bf[nj][kk][0], a, 0, 0, 0);
          a = __builtin_amdgcn_mfma_f32_16x16x32_bf16(Af[mi][0], Bf[nj][kk][1], a, 0, 0, 0);
          a = __builtin_amdgcn_mfma_f32_16x16x32_bf16(Af[mi][1], Bf[nj][kk][0], a, 0, 0, 0);
          a = __builtin_amdgcn_mfma_f32_16x16x32_bf16(Af[mi][0], Bf[nj][kk][2], a, 0, 0, 0);
          a = __builtin_amdgcn_mfma_f32_16x16x32_bf16(Af[mi][1], Bf[nj][kk][1], a, 0, 0, 0);
          a = __builtin_amdgcn_mfma_f32_16x16x32_bf16(Af[mi][2], Bf[nj][kk][0], a, 0, 0, 0);
          accP[mi][nj] = a;
        }
    }
    #pragma unroll
    for (int mi = 0; mi < 2; ++mi)
      #pragma unroll
      for (int r = 0; r < 4; ++r) {
        const float wv = iw[(long long)(l0 + wr * 32 + mi * 16 + g * 4 + r) * 64 + h];
        #pragma unroll
        for (int nj = 0; nj < 2; ++nj)
          accS[mi][nj][r] = fmaf(wv, fmaxf(accP[mi][nj][r], 0.f), accS[mi][nj][r]);
      }
    __syncthreads();
    cur ^= 1;
  }
#undef STAGE_IQ
  #pragma unroll
  for (int mi = 0; mi < 2; ++mi)
    #pragma unroll
    for (int nj = 0; nj < 2; ++nj) {
      const int col = s0 + wc * 32 + nj * 16 + (t & 15);
      #pragma unroll
      for (int r = 0; r < 4; ++r) {
        const int row = l0 + wr * 32 + mi * 16 + g * 4 + r;
        S[(long long)row * 1024 + col] = (col <= row) ? accS[mi][nj][r] : NEG_BIG;
      }
    }
}

// ---------------------------------------------------------------------------
// per-row top-k (radix select, f32 exact)
// ---------------------------------------------------------------------------
__global__ __launch_bounds__(256) void topk_rows(
    const float* __restrict__ S, int* __restrict__ idx_out, int* __restrict__ cnt_out)
{
  const int l = blockIdx.x;
  const int n = l + 1;
  const int k = n < 256 ? n : 256;
  if (threadIdx.x == 0) cnt_out[l] = k;
  if (k == n) {
    for (int s = threadIdx.x; s < n; s += 256) idx_out[l * 256 + s] = s;
    return;
  }
  __shared__ unsigned u[1024];
  __shared__ int hist[256];
  __shared__ unsigned sh_pref;
  __shared__ int sh_rem, cG, cE;
  const float* row = S + (long long)l * 1024;
  for (int s = threadIdx.x; s < n; s += 256) {
    unsigned b = __float_as_uint(row[s]);
    u[s] = (b & 0x80000000u) ? ~b : (b | 0x80000000u);
  }
  __syncthreads();
  unsigned prefix = 0;
  int rem = k;
  for (int pass = 0; pass < 4; ++pass) {
    const int shift = 24 - 8 * pass;
    hist[threadIdx.x] = 0;
    __syncthreads();
    const unsigned hiMask = (pass == 0) ? 0u : (0xFFFFFFFFu << (shift + 8));
    for (int s = threadIdx.x; s < n; s += 256) {
      unsigned uv = u[s];
      if ((uv & hiMask) == (prefix & hiMask))
        atomicAdd(&hist[(uv >> shift) & 255], 1);
    }
    __syncthreads();
    if (threadIdx.x == 0) {
      int cum = 0, b = 255;
      for (; b > 0; --b) { cum += hist[b]; if (cum >= rem) break; }
      if (cum < rem) cum += hist[0];
      sh_rem  = rem - (cum - hist[b]);
      sh_pref = prefix | ((unsigned)b << shift);
    }
    __syncthreads();
    prefix = sh_pref;
    rem = sh_rem;
    __syncthreads();
  }
  if (threadIdx.x == 0) { cG = 0; cE = 0; }
  __syncthreads();
  for (int s = threadIdx.x; s < n; s += 256) {
    if (u[s] > prefix) { int p = atomicAdd(&cG, 1); idx_out[l * 256 + p] = s; }
  }
  __syncthreads();
  const int base = cG;
  for (int s = threadIdx.x; s < n; s += 256) {
    if (u[s] == prefix) {
      int p = atomicAdd(&cE, 1);
      if (p < rem) idx_out[l * 256 + base + p] = s;
    }
  }
}

// ---------------------------------------------------------------------------
// qeh pe part copy (bf16->bf16): qeh[l][h][512+p] = qbuf_bf[l][h*192+128+p]
// ---------------------------------------------------------------------------
__global__ void pe_copy(const unsigned short* __restrict__ qb, unsigned short* __restrict__ qeh)
{
  const int l = blockIdx.x, t = threadIdx.x;
  const int h = t >> 3, p0 = (t & 7) * 8;
  const uint4 v = *reinterpret_cast<const uint4*>(qb + (long long)l * 6144 + h * 192 + 128 + p0);
  *reinterpret_cast<uint4*>(qeh + (long long)l * 18432 + h * 576 + 512 + p0) = v;
}

// ---------------------------------------------------------------------------
// Latent sparse attention, one block per l.
// ---------------------------------------------------------------------------
__global__ __launch_bounds__(256) void latent_attn(
    const unsigned short* __restrict__ qeh,  // [1024][32][576] bf16
    const float* __restrict__ ckv,           // [1024][576] f32
    const unsigned short* __restrict__ ckv_bf,
    const int* __restrict__ tk_idx, const int* __restrict__ tk_cnt,
    unsigned short* __restrict__ lat_bf)     // [1024][32][512] bf16
{
  const int L_ = blockIdx.x;
  const int t = threadIdx.x;
  const int w = t >> 6;
  const int cnt = tk_cnt[L_];
  __shared__ int jl[256];
  __shared__ float S[32][264];
  jl[t] = (t < cnt) ? tk_idx[L_ * 256 + t] : 0;
  __syncthreads();

  f32x4 acc[2][4] = {};
  int jr[4];
  #pragma unroll
  for (int nj = 0; nj < 4; ++nj) jr[nj] = jl[w * 64 + nj * 16 + (t & 15)];
  const unsigned short* ab = qeh + (long long)L_ * 18432;
  const int ko_lane = ((t >> 4) & 3) * 8;
  for (int ks = 0; ks < 18; ++ks) {
    const int k0 = ks * 32 + ko_lane;
    bf16x8 a0 = *reinterpret_cast<const bf16x8*>(ab + (t & 15) * 576 + k0);
    bf16x8 a1 = *reinterpret_cast<const bf16x8*>(ab + ((t & 15) + 16) * 576 + k0);
    #pragma unroll
    for (int nj = 0; nj < 4; ++nj) {
      bf16x8 bfr = *reinterpret_cast<const bf16x8*>(ckv_bf + (long long)jr[nj] * 576 + k0);
      acc[0][nj] = __builtin_amdgcn_mfma_f32_16x16x32_bf16(a0, bfr, acc[0][nj], 0, 0, 0);
      acc[1][nj] = __builtin_amdgcn_mfma_f32_16x16x32_bf16(a1, bfr, acc[1][nj], 0, 0, 0);
    }
  }
  const int rbase = ((t >> 4) & 3) * 4;
  #pragma unroll
  for (int mi = 0; mi < 2; ++mi)
    #pragma unroll
    for (int nj = 0; nj < 4; ++nj) {
      const int col = w * 64 + nj * 16 + (t & 15);
      #pragma unroll
      for (int r = 0; r < 4; ++r)
        S[mi * 16 + rbase + r][col] = (col < cnt) ? acc[mi][nj][r] * SCALE_ATTN : NEG_BIG;
    }
  __syncthreads();

  {
    const int row = t >> 3, lane = t & 7;
    float mx = NEG_BIG;
    for (int j = lane; j < 256; j += 8) mx = fmaxf(mx, S[row][j]);
    #pragma unroll
    for (int o = 1; o < 8; o <<= 1) mx = fmaxf(mx, __shfl_xor(mx, o));
    float sum = 0.f;
    for (int j = lane; j < 256; j += 8) {
      float e = __expf(S[row][j] - mx);
      S[row][j] = e;
      sum += e;
    }
    #pragma unroll
    for (int o = 1; o < 8; o <<= 1) sum += __shfl_xor(sum, o);
    const float inv = 1.f / sum;
    for (int j = lane; j < 256; j += 8) S[row][j] *= inv;
  }
  __syncthreads();

  const int d4 = t & 127, h0 = (t >> 7) * 16;
  float4 o[16];
  #pragma unroll
  for (int i = 0; i < 16; ++i) o[i] = make_float4(0.f, 0.f, 0.f, 0.f);
  for (int j = 0; j < cnt; ++j) {
    const int jj = jl[j];
    const float4 c4 = *reinterpret_cast<const float4*>(ckv + (long long)jj * 576 + d4 * 4);
    #pragma unroll
    for (int i = 0; i < 16; ++i) {
      const float p = S[h0 + i][j];
      o[i].x = fmaf(p, c4.x, o[i].x);
      o[i].y = fmaf(p, c4.y, o[i].y);
      o[i].z = fmaf(p, c4.z, o[i].z);
      o[i].w = fmaf(p, c4.w, o[i].w);
    }
  }
  unsigned short* ob = lat_bf + (long long)L_ * 16384 + d4 * 4;
  #pragma unroll
  for (int i = 0; i < 16; ++i) {
    ushort4 pk;
    pk.x = f2bf(o[i].x); pk.y = f2bf(o[i].y); pk.z = f2bf(o[i].z); pk.w = f2bf(o[i].w);
    *reinterpret_cast<ushort4*>(ob + (h0 + i) * 512) = pk;
  }
}

// ---------------------------------------------------------------------------
extern "C" void kernel_launch(void* const* d_in, const int* in_sizes, int n_in,
                              void* d_out, int out_size, void* d_ws, size_t ws_size,
                              hipStream_t stream)
{
  const float* x        = (const float*)d_in[0];
  const float* W_qa     = (const float*)d_in[2];
  const float* qa_ln_w  = (const float*)d_in[3];
  const float* W_qb     = (const float*)d_in[4];
  const float* W_kva    = (const float*)d_in[5];
  const float* kva_ln_w = (const float*)d_in[6];
  const float* W_eq     = (const float*)d_in[7];   // [32][512][128]
  const float* W_uo     = (const float*)d_in[8];   // [32][128][512]
  const float* W_o      = (const float*)d_in[9];   // [4096][4096]
  const float* idx_wqb  = (const float*)d_in[10];  // [8192][1536]
  const float* idx_wk   = (const float*)d_in[11];  // [128][4096]
  const float* idx_klnw = (const float*)d_in[12];
  const float* idx_klnb = (const float*)d_in[13];
  const float* idx_wprj = (const float*)d_in[14];  // [64][4096]
  float* out = (float*)d_out;

  char* W = (char*)d_ws;
  // A: part_qa (25.2MB) -> lat_bf (33.5MB)
  float*          part_qa = (float*)(W + 0);
  unsigned short* lat_bf  = (unsigned short*)(W + 0);
  // B: qr
  float*          qr      = (float*)(W + 33554432);
  // C: ckv ; D: ckv_bf
  float*          ckv     = (float*)(W + 39845888);
  unsigned short* ckv_bf  = (unsigned short*)(W + 42205184);
  // E: iq levels (3x16.78MB) -> qeh_bf (37.7MB) -> W_o_bf (33.5MB)
  unsigned short* iqh     = (unsigned short*)(W + 43384832);
  unsigned short* iqm     = (unsigned short*)(W + 43384832 + 16777216);
  unsigned short* iql     = (unsigned short*)(W + 43384832 + 33554432);
  unsigned short* qeh_bf  = (unsigned short*)(W + 43384832);
  unsigned short* W_o_bf  = (unsigned short*)(W + 43384832);
  // F: part_wk/part_wp -> W_qb_bf -> {W_eq_bf, W_uo_bf, attn_bf}
  float*          part_wk = (float*)(W + 93716480);
  float*          part_wp = (float*)(W + 93716480 + 4194304);
  unsigned short* W_qb_bf = (unsigned short*)(W + 93716480);
  unsigned short* W_eq_bf = (unsigned short*)(W + 93716480);
  unsigned short* W_uo_bf = (unsigned short*)(W + 93716480 + 4194304);
  unsigned short* attn_bf = (unsigned short*)(W + 93716480 + 8388608);
  // G: qr_bf ; H: qbuf_bf
  unsigned short* qr_bf   = (unsigned short*)(W + 112590848);
  unsigned short* qbuf_bf = (unsigned short*)(W + 115736576);
  // I: indexer smalls
  float* ikbuf   = (float*)(W + 128319488);
  float* iwbuf   = (float*)(W + 128843776);
  unsigned short* ikh = (unsigned short*)(W + 129105920);
  unsigned short* ikm = (unsigned short*)(W + 129105920 + 262144);
  unsigned short* ikl = (unsigned short*)(W + 129105920 + 524288);
  float* iscores = (float*)(W + 129892352);
  int*   tk_idx  = (int*)(W + 134086656);
  int*   tk_cnt  = (int*)(W + 135135232);

  // 1) qr = rmsnorm(x @ W_qa.T)  -- f32, splitK=4
  gemm_f32_128<<<dim3(12, 8, 4), 256, 0, stream>>>(
      x, W_qa, part_qa, 1024, 4096, 4096, 1536, 1024, 1024, 1024LL * 1536, 1.f);
  reduce_sk<<<(393216 + 255) / 256, 256, 0, stream>>>(part_qa, qr, 393216, 4);
  rmsnorm_rows<<<1024, 256, 0, stream>>>(qr, qa_ln_w, 1536, 1536, 1e-6f);

  // 2) ckv = x @ W_kva.T ; rmsnorm ; rope k_pe
  gemm_f32<true><<<dim3(9, 16, 1), 256, 0, stream>>>(
      x, W_kva, ckv, 1024, 576, 4096, 4096, 4096, 576, 0, 0, 0, 1.f);
  rmsnorm_rows<<<1024, 256, 0, stream>>>(ckv, kva_ln_w, 512, 576, 1e-6f);
  rope_apply<<<dim3(1024, 1), 32, 0, stream>>>(ckv, 576, 0, 512);

  // 3) ik = rope(layernorm(x @ idx_wk.T)) ; 3-level split
  gemm_f32<true><<<dim3(2, 16, 8), 256, 0, stream>>>(
      x, idx_wk, part_wk, 1024, 128, 512, 4096, 4096, 128, 512, 512, 131072, 1.f);
  reduce_sk<<<(32768 + 255) / 256, 256, 0, stream>>>(part_wk, ikbuf, 32768, 8);
  layernorm_rows<<<1024, 128, 0, stream>>>(ikbuf, idx_klnw, idx_klnb, 1e-5f);
  rope_apply<<<dim3(1024, 1), 32, 0, stream>>>(ikbuf, 128, 0, 0);
  split3_k<<<(32768 + 255) / 256, 256, 0, stream>>>(ikbuf, ikh, ikm, ikl, 32768);

  // 4) iw = x @ idx_wproj.T * scale  -- splitK=16
  gemm_f32<true><<<dim3(1, 16, 16), 256, 0, stream>>>(
      x, idx_wprj, part_wp, 1024, 64, 256, 4096, 4096, 64, 256, 256, 65536, IW_SCALE);
  reduce_sk<<<(16384 + 255) / 256, 256, 0, stream>>>(part_wp, iwbuf, 16384, 16);

  // 5) qbuf_bf = rope_pe(qr_bf @ W_qb_bf.T)  [bf16 MFMA, fused rope]
  f2bf_k<<<(2359296 + 255) / 256, 256, 0, stream>>>(W_qb, W_qb_bf, 2359296);
  f2bf_k<<<(393216 + 255) / 256, 256, 0, stream>>>(qr, qr_bf, 393216);
  gemm_bf16nt<true, true><<<dim3(48, 8, 1), 256, 0, stream>>>(
      qr_bf, W_qb_bf, qbuf_bf, 1536, 1536, 1536, 6144, 0, 0, 0);

  // 6) iq levels = split3(rope(qr @ idx_wqb.T))  [fused epilogue]
  gemm_iq<<<dim3(64, 8, 1), 256, 0, stream>>>(qr, idx_wqb, iqh, iqm, iql);

  // 7) indexer scores (6-term split-bf16 MFMA) + topk
  indexer_mfma<<<dim3(16, 16), 256, 0, stream>>>(
      iqh, iqm, iql, ikh, ikm, ikl, iwbuf, iscores);
  topk_rows<<<1024, 256, 0, stream>>>(iscores, tk_idx, tk_cnt);

  // 8) converts for attention path
  f2bf_k<<<(147456 + 255) / 256, 256, 0, stream>>>(ckv, ckv_bf, 147456);
  f2bf_k<<<(524288 + 255) / 256, 256, 0, stream>>>(W_eq, W_eq_bf, 524288);
  f2bf_k<<<(524288 + 255) / 256, 256, 0, stream>>>(W_uo, W_uo_bf, 524288);

  // 9) q_eff[l,h,:512] = q_nope . W_eq[h]^T (batched bf16) ; append pe
  gemm_bf16nt<true, false><<<dim3(4, 8, 32), 256, 0, stream>>>(
      qbuf_bf, W_eq_bf, qeh_bf, 128, 6144, 128, 18432, 192, 65536, 576);
  pe_copy<<<1024, 256, 0, stream>>>(qbuf_bf, qeh_bf);

  // 10) latent sparse attention
  latent_attn<<<1024, 256, 0, stream>>>(qeh_bf, ckv, ckv_bf, tk_idx, tk_cnt, lat_bf);

  // 11) out_head = lat_out @ W_uo[h].T (batched bf16 -> bf16)
  gemm_bf16nt<true, false><<<dim3(1, 8, 32), 256, 0, stream>>>(
      lat_bf, W_uo_bf, attn_bf, 512, 16384, 512, 4096, 512, 65536, 128);

  // 12) out = attn @ W_o.T (bf16 -> f32)
  f2bf_k<<<(4194304 + 255) / 256, 256, 0, stream>>>(W_o, W_o_bf, 4194304);
  gemm_bf16nt<false, false><<<dim3(32, 8, 1), 256, 0, stream>>>(
      attn_bf, W_o_bf, out, 4096, 4096, 4096, 4096, 0, 0, 0);
}